// Round 1
// 85.462 us; speedup vs baseline: 1.0712x; 1.0712x over previous
//
#include <hip/hip_runtime.h>
#include <math.h>

#define HH 256
#define WW 512
#define HWN (HH * WW)          // 131072
#define NPR 512
#define NSR 8
#define CHUNK 512              // elements per chunk (= one HDRI row)
#define NCHUNK 256             // HWN / CHUNK
#define RPB 16                 // rays per block (chunksum kernel)
#define CPB 4                  // chunks per block = waves per block

// ---------------- DPP-based fp64 cross-lane (no ds_bpermute traffic) --------
// Moves the two 32-bit halves with v_mov_b32_dpp; invalid/masked lanes yield
// +0.0 so the add is a no-op there. Association differs from the old shfl
// trees only at the fp64 rounding level (~1e-16 rel) — crossing decisions
// are unchanged.
template<int CTRL, int RM>
static __device__ __forceinline__ double dpp_mov_f64(double x) {
    long long b = __double_as_longlong(x);
    int plo = __builtin_amdgcn_update_dpp(0, (int)b,         CTRL, RM, 0xF, true);
    int phi = __builtin_amdgcn_update_dpp(0, (int)(b >> 32), CTRL, RM, 0xF, true);
    return __longlong_as_double(((long long)phi << 32) | (unsigned int)plo);
}

// Inclusive wave64 prefix sum; lane 63 ends with the wave total.
// row_shr:1/2/4/8 builds within-row (16-lane) inclusive prefixes,
// row_bcast:15 (rows 1,3) and row_bcast:31 (rows 2,3) stitch rows together.
static __device__ __forceinline__ double wave_iscan_f64(double x) {
    x += dpp_mov_f64<0x111, 0xF>(x);   // row_shr:1
    x += dpp_mov_f64<0x112, 0xF>(x);   // row_shr:2
    x += dpp_mov_f64<0x114, 0xF>(x);   // row_shr:4
    x += dpp_mov_f64<0x118, 0xF>(x);   // row_shr:8
    x += dpp_mov_f64<0x142, 0xA>(x);   // row_bcast:15 -> rows 1,3
    x += dpp_mov_f64<0x143, 0xC>(x);   // row_bcast:31 -> rows 2,3
    return x;
}

// Granule mapping: 4 consecutive elements <-> 3 float4 loads (12 floats).
// For granule base element b (b*3 % 4 == 0), lane l covers elems b+4l..b+4l+3
// via float4 indices (3*b/4 + 3l + {0,1,2}). Fully coalesced.
__device__ __forceinline__ void load_granule4(const float4* __restrict__ envs4,
                                              const float4* __restrict__ dir4,
                                              int f4base,
                                              float inten[4], float dx[4],
                                              float dy[4], float dz[4]) {
    float4 e0 = envs4[f4base + 0], e1 = envs4[f4base + 1], e2 = envs4[f4base + 2];
    float4 d0 = dir4[f4base + 0],  d1 = dir4[f4base + 1],  d2 = dir4[f4base + 2];
    inten[0] = sqrtf(e0.x * e0.x + e0.y * e0.y + e0.z * e0.z);
    inten[1] = sqrtf(e0.w * e0.w + e1.x * e1.x + e1.y * e1.y);
    inten[2] = sqrtf(e1.z * e1.z + e1.w * e1.w + e2.x * e2.x);
    inten[3] = sqrtf(e2.y * e2.y + e2.z * e2.z + e2.w * e2.w);
    dx[0] = d0.x; dy[0] = d0.y; dz[0] = d0.z;
    dx[1] = d0.w; dy[1] = d1.x; dz[1] = d1.y;
    dx[2] = d1.z; dy[2] = d1.w; dz[2] = d2.x;
    dx[3] = d2.y; dy[3] = d2.z; dz[3] = d2.w;
}

// ---------------- Kernel 1: chunk sums S[p][c], 16-ray reuse, raw inputs ----
__global__ __launch_bounds__(256)
void chunksum_kernel(const float* __restrict__ normal,
                     const float4* __restrict__ envs4,
                     const float4* __restrict__ dir4,
                     double* __restrict__ S) {
    const int wave = threadIdx.x >> 6;
    const int lane = threadIdx.x & 63;
    const int c  = blockIdx.x * CPB + wave;
    const int r0 = blockIdx.y * RPB;

    float rx[RPB], ry[RPB], rz[RPB];
#pragma unroll
    for (int i = 0; i < RPB; ++i) {
        int r = r0 + i;
        rx[i] =  normal[3 * r + 0];
        ry[i] = -normal[3 * r + 2];
        rz[i] = -normal[3 * r + 1];
    }

    float acc[RPB];
#pragma unroll
    for (int i = 0; i < RPB; ++i) acc[i] = 0.0f;

#pragma unroll
    for (int g = 0; g < 2; ++g) {
        const int f4base = c * 384 + g * 192 + 3 * lane;
        float inten[4], dx[4], dy[4], dz[4];
        load_granule4(envs4, dir4, f4base, inten, dx, dy, dz);
#pragma unroll
        for (int j = 0; j < 4; ++j) {
#pragma unroll
            for (int i = 0; i < RPB; ++i) {
                float m = fmaf(rx[i], dx[j], fmaf(ry[i], dy[j], rz[i] * dz[j]));
                m = fminf(fmaxf(m, 0.0f), 1.0f);
                acc[i] = fmaf(inten[j], m, acc[i]);
            }
        }
    }

    // fp64 wave reduction via DPP (was: 16 x 6-step fp64 shfl = ~192 ds_bpermute)
#pragma unroll
    for (int i = 0; i < RPB; ++i) {
        double a = wave_iscan_f64((double)acc[i]);
        if (lane == 63) S[(r0 + i) * NCHUNK + c] = a;
    }
}

// ---------------- Kernel 2: per-ray CDF sampling, raw inputs ----------------
__global__ __launch_bounds__(256)
void sample_kernel(const float* __restrict__ normal,
                   const float4* __restrict__ envs4,
                   const float4* __restrict__ dir4,
                   const double* __restrict__ S,
                   const float* __restrict__ ps,
                   float* __restrict__ out) {
    const int p = blockIdx.x;
    const int t = threadIdx.x;
    const int wave = t >> 6;
    const int lane = t & 63;
    const float* envs = (const float*)envs4;
    const float* dirm = (const float*)dir4;

    // normal_r = (nx, -nz, -ny)   (rotz = I at angle 0)
    const float rx =  normal[3 * p + 0];
    const float ry = -normal[3 * p + 2];
    const float rz = -normal[3 * p + 1];

    __shared__ double pref[NCHUNK];  // inclusive prefix of chunk sums
    __shared__ double wsum[4];

    // parallel fp64 scan of the 256 chunk sums (DPP, no LDS bpermute)
    double v = S[p * NCHUNK + t];
    double sc = wave_iscan_f64(v);
    if (lane == 63) wsum[wave] = sc;
    __syncthreads();
    double add = 0.0;
    for (int w2 = 0; w2 < wave; ++w2) add += wsum[w2];
    pref[t] = sc + add;
    __syncthreads();

    const double total = pref[NCHUNK - 1];
    const float totalF = (float)total;
    const float px = 2.0f / (float)HWN;

    // each wave processes samples (wave) and (wave+4)
    for (int si = 0; si < 2; ++si) {
        const int s = wave + si * 4;
        const double target = (double)ps[p * NSR + s] * total;

        // first chunk c with pref[c] > target (wave-uniform binary search)
        int lo = 0, hi = NCHUNK;
        while (lo < hi) {
            int mid = (lo + hi) >> 1;
            if (pref[mid] > target) hi = mid; else lo = mid + 1;
        }
        const int c = lo;

        if (c >= NCHUNK) {
            if (lane == 0) {
                int ch = HWN - 1;
                float ex = envs[3 * ch], ey = envs[3 * ch + 1], ez = envs[3 * ch + 2];
                float inten = sqrtf(ex * ex + ey * ey + ez * ez);
                float m = fmaf(rx, dirm[3 * ch], fmaf(ry, dirm[3 * ch + 1], rz * dirm[3 * ch + 2]));
                m = fminf(fmaxf(m, 0.0f), 1.0f);
                float modu = inten * m;
                float qx = modu / totalF + 1e-7f;
                float ratio = px * m / qx;
                int o = p * NSR + s;
                out[o] = (float)(ch / WW);
                out[NPR * NSR + o] = (float)(ch % WW);
                out[2 * NPR * NSR + o] = ratio;
            }
            continue;
        }

        const double basePref = (c > 0) ? pref[c - 1] : 0.0;
        const int cbase = c * CHUNK;

        // two granules of 4 consecutive elements per lane
        float mvals[8], modv[8];
        double lsum[2];
#pragma unroll
        for (int g = 0; g < 2; ++g) {
            const int f4base = c * 384 + g * 192 + 3 * lane;
            float inten[4], dx[4], dy[4], dz[4];
            load_granule4(envs4, dir4, f4base, inten, dx, dy, dz);
            double ls = 0.0;
#pragma unroll
            for (int j = 0; j < 4; ++j) {
                float m = fmaf(rx, dx[j], fmaf(ry, dy[j], rz * dz[j]));
                m = fminf(fmaxf(m, 0.0f), 1.0f);
                modv[4 * g + j] = m;
                mvals[4 * g + j] = inten[j] * m;
                ls += (double)mvals[4 * g + j];
            }
            lsum[g] = ls;
        }

        // inclusive DPP scans per granule (was: 2 x 6-step fp64 shfl_up)
        double s0 = wave_iscan_f64(lsum[0]);
        double s1 = wave_iscan_f64(lsum[1]);
        const double g0tot = __shfl(s0, 63);
        const double cum0base = basePref + (s0 - lsum[0]);
        const double cum1base = basePref + g0tot + (s1 - lsum[1]);

        int myidx = HWN;
        float mymod = 0.0f, mymodu = 0.0f;
        double cum = cum0base;
#pragma unroll
        for (int j = 0; j < 4 && myidx == HWN; ++j) {
            cum += (double)mvals[j];
            if (cum > target) { myidx = cbase + 4 * lane + j; mymod = modv[j]; mymodu = mvals[j]; }
        }
        if (myidx == HWN) {
            cum = cum1base;
#pragma unroll
            for (int j = 0; j < 4 && myidx == HWN; ++j) {
                cum += (double)mvals[4 + j];
                if (cum > target) { myidx = cbase + 256 + 4 * lane + j; mymod = modv[4 + j]; mymodu = mvals[4 + j]; }
            }
        }

        // min-index reduce over the wave, carrying payload
        int widx = myidx;
        float wmod = mymod, wmodu = mymodu;
#pragma unroll
        for (int off = 32; off > 0; off >>= 1) {
            int oi = __shfl_down(widx, off);
            float om = __shfl_down(wmod, off);
            float ou = __shfl_down(wmodu, off);
            if (oi < widx) { widx = oi; wmod = om; wmodu = ou; }
        }

        if (lane == 0) {
            int ch = widx;
            if (ch >= HWN) {
                // rounding edge: no element exceeded target; take chunk end
                ch = cbase + CHUNK - 1;
                float ex = envs[3 * ch], ey = envs[3 * ch + 1], ez = envs[3 * ch + 2];
                float inten = sqrtf(ex * ex + ey * ey + ez * ez);
                float m = fmaf(rx, dirm[3 * ch], fmaf(ry, dirm[3 * ch + 1], rz * dirm[3 * ch + 2]));
                m = fminf(fmaxf(m, 0.0f), 1.0f);
                wmod = m;
                wmodu = inten * m;
            }
            float qx = wmodu / totalF + 1e-7f;
            float ratio = px * wmod / qx;
            int o = p * NSR + s;
            out[o] = (float)(ch / WW);
            out[NPR * NSR + o] = (float)(ch % WW);
            out[2 * NPR * NSR + o] = ratio;
        }
    }
}

extern "C" void kernel_launch(void* const* d_in, const int* in_sizes, int n_in,
                              void* d_out, int out_size, void* d_ws, size_t ws_size,
                              hipStream_t stream) {
    const float* normal  = (const float*)d_in[0];
    const float* envs    = (const float*)d_in[1];
    const float* dirmap  = (const float*)d_in[2];
    const float* ps      = (const float*)d_in[3];
    // d_in[4] = env_idxs; NUM_ENVS == 1 so every index is 0.
    float* out = (float*)d_out;

    double* S = (double*)d_ws;   // NPR * NCHUNK * 8 B = 1 MiB

    chunksum_kernel<<<dim3(NCHUNK / CPB, NPR / RPB), 256, 0, stream>>>(
        normal, (const float4*)envs, (const float4*)dirmap, S);
    sample_kernel<<<NPR, 256, 0, stream>>>(
        normal, (const float4*)envs, (const float4*)dirmap, S, ps, out);
}